// Round 1
// baseline (1133.790 us; speedup 1.0000x reference)
//
#include <hip/hip_runtime.h>
#include <float.h>

#define BB 32
#define QQ 900
#define TT 300
#define CC 256

// ---------------------------------------------------------------------------
// Kernel A: per-(b,q) softmax stats: rowmax and sum(exp(l - max))
// ---------------------------------------------------------------------------
__global__ __launch_bounds__(256)
void softmax_stats_kernel(const float* __restrict__ logits, float2* __restrict__ stats)
{
    const int row = blockIdx.x;                 // b*QQ + q
    const float* L = logits + (size_t)row * CC;
    const int tid = threadIdx.x;
    float x = L[tid];

    __shared__ float sredm[4];
    __shared__ float sreds[4];

    float m = x;
    #pragma unroll
    for (int off = 32; off > 0; off >>= 1)
        m = fmaxf(m, __shfl_down(m, off, 64));
    if ((tid & 63) == 0) sredm[tid >> 6] = m;
    __syncthreads();
    m = fmaxf(fmaxf(sredm[0], sredm[1]), fmaxf(sredm[2], sredm[3]));

    float s = expf(x - m);
    #pragma unroll
    for (int off = 32; off > 0; off >>= 1)
        s += __shfl_down(s, off, 64);
    if ((tid & 63) == 0) sreds[tid >> 6] = s;
    __syncthreads();
    if (tid == 0)
        stats[row] = make_float2(m, sreds[0] + sreds[1] + sreds[2] + sreds[3]);
}

// ---------------------------------------------------------------------------
// Kernel B: cost matrix, 32q x 32t tiles. Writes Cmat [b][q][t] coalesced and
// (via LDS transpose) CT [b][t][q] coalesced.
// ---------------------------------------------------------------------------
__global__ __launch_bounds__(256)
void cost_kernel(const float* __restrict__ logits,
                 const float* __restrict__ pboxes,
                 const float* __restrict__ pcut,
                 const int*   __restrict__ tlabels,
                 const float* __restrict__ tboxes,
                 const float* __restrict__ tcut,
                 const float2* __restrict__ stats,
                 float* __restrict__ Cmat,
                 float* __restrict__ CT)
{
    const int b  = blockIdx.z;
    const int q0 = blockIdx.x * 32;
    const int t0 = blockIdx.y * 32;
    const int tid = threadIdx.x;

    __shared__ float s_pb[32][4], s_tb[32][4];
    __shared__ float s_pc[32], s_tc[32], s_pm[32], s_ps[32], s_pa[32], s_ta[32];
    __shared__ int   s_tl[32];
    __shared__ float s_tile[32][33];

    if (tid < 32) {
        int q = q0 + tid;
        if (q < QQ) {
            const float* pb = pboxes + ((size_t)b * QQ + q) * 4;
            float x1 = pb[0], y1 = pb[1], x2 = pb[2], y2 = pb[3];
            s_pb[tid][0] = x1; s_pb[tid][1] = y1; s_pb[tid][2] = x2; s_pb[tid][3] = y2;
            s_pa[tid] = (x2 - x1) * (y2 - y1);
            s_pc[tid] = pcut[(size_t)b * QQ + q];
            float2 st = stats[(size_t)b * QQ + q];
            s_pm[tid] = st.x; s_ps[tid] = st.y;
        }
    } else if (tid < 64) {
        int tl = tid - 32;
        int t = t0 + tl;
        if (t < TT) {
            const float* tb = tboxes + ((size_t)b * TT + t) * 4;
            float x1 = tb[0], y1 = tb[1], x2 = tb[2], y2 = tb[3];
            s_tb[tl][0] = x1; s_tb[tl][1] = y1; s_tb[tl][2] = x2; s_tb[tl][3] = y2;
            s_ta[tl] = (x2 - x1) * (y2 - y1);
            s_tc[tl] = tcut[(size_t)b * TT + t];
            s_tl[tl] = tlabels[(size_t)b * TT + t];
        }
    }
    __syncthreads();

    const int tl = tid & 31;
    const int t  = t0 + tl;
    #pragma unroll
    for (int k = 0; k < 4; ++k) {
        int ql = (tid >> 5) + 8 * k;
        int q  = q0 + ql;
        if (q < QQ && t < TT) {
            float lg = logits[((size_t)b * QQ + q) * CC + s_tl[tl]];
            float cclass = -(expf(lg - s_pm[ql]) / s_ps[ql]);

            float px1 = s_pb[ql][0], py1 = s_pb[ql][1], px2 = s_pb[ql][2], py2 = s_pb[ql][3];
            float tx1 = s_tb[tl][0], ty1 = s_tb[tl][1], tx2 = s_tb[tl][2], ty2 = s_tb[tl][3];

            float l1 = fabsf(px1 - tx1) + fabsf(py1 - ty1) + fabsf(px2 - tx2) + fabsf(py2 - ty2);

            float iw = fmaxf(fminf(px2, tx2) - fmaxf(px1, tx1), 0.0f);
            float ih = fmaxf(fminf(py2, ty2) - fmaxf(py1, ty1), 0.0f);
            float inter = iw * ih;
            float uni = s_pa[ql] + s_ta[tl] - inter;
            float iou = inter / uni;

            float ew = fmaxf(fmaxf(px2, tx2) - fminf(px1, tx1), 0.0f);
            float eh = fmaxf(fmaxf(py2, ty2) - fminf(py1, ty1), 0.0f);
            float enc = ew * eh;
            float giou = iou - (enc - uni) / enc;

            float cost = 5.0f * l1 + cclass - 2.0f * giou
                       + 2.0f * fabsf(s_pc[ql] - s_tc[tl]);

            Cmat[((size_t)b * QQ + q) * TT + t] = cost;
            s_tile[ql][tl] = cost;
        }
    }
    __syncthreads();

    if (CT != nullptr) {
        #pragma unroll
        for (int k = 0; k < 4; ++k) {
            int tl2 = (tid >> 5) + 8 * k;
            int ql2 = tid & 31;
            int t2 = t0 + tl2, q2 = q0 + ql2;
            if (q2 < QQ && t2 < TT)
                CT[((size_t)b * TT + t2) * QQ + q2] = s_tile[ql2][tl2];
        }
    }
}

// ---------------------------------------------------------------------------
// Kernel C: Jonker-Volgenant shortest-augmenting-path LSA, one block per batch.
// Solves cost^T: n = TT rows (targets), m = QQ cols (queries). Double precision
// to match the numpy float64 reference. Parallel O(m) sweeps + argmin reduce.
// ---------------------------------------------------------------------------
#define SOLVER_THREADS 512
#define NWAVES (SOLVER_THREADS / 64)

__global__ __launch_bounds__(SOLVER_THREADS)
void lsa_kernel(const float* __restrict__ Mbase,
                long long batchStride, long long rowStride, long long colStride,
                float* __restrict__ outq, float* __restrict__ outt)
{
    const int b = blockIdx.x;
    const float* M = Mbase + (size_t)b * batchStride;
    const int tid = threadIdx.x;
    const double INFD = 1e300;

    __shared__ double u[TT + 1];
    __shared__ double v[QQ + 1];
    __shared__ double minv[QQ + 1];
    __shared__ int    p[QQ + 1];
    __shared__ int    way[QQ + 1];
    __shared__ unsigned char used[QQ + 1];
    __shared__ int    usedList[TT + 2];
    __shared__ double redV[NWAVES];
    __shared__ int    redJ[NWAVES];
    __shared__ int    s_cnt;

    for (int j = tid; j <= QQ; j += SOLVER_THREADS) { v[j] = 0.0; p[j] = 0; }
    for (int i = tid; i <= TT; i += SOLVER_THREADS) u[i] = 0.0;
    __syncthreads();

    for (int i = 1; i <= TT; ++i) {
        for (int j = tid; j <= QQ; j += SOLVER_THREADS) { minv[j] = INFD; used[j] = 0; }
        if (tid == 0) { p[0] = i; s_cnt = 0; }
        __syncthreads();

        int j0 = 0;
        while (true) {
            const int i0 = p[j0];
            const double ui0 = u[i0];
            const float* Mrow = M + (long long)(i0 - 1) * rowStride;

            if (tid == 0) { usedList[s_cnt] = j0; s_cnt = s_cnt + 1; used[j0] = 1; }

            // sweep free columns: update minv/way, track local argmin of minv
            double bv = INFD; int bj = QQ + 1;
            for (int j = tid + 1; j <= QQ; j += SOLVER_THREADS) {
                if (j == j0 || used[j]) continue;
                double cur = (double)Mrow[(long long)(j - 1) * colStride] - ui0 - v[j];
                double mv = minv[j];
                if (cur < mv) { mv = cur; minv[j] = cur; way[j] = j0; }
                if (mv < bv) { bv = mv; bj = j; }   // strict <: keeps lowest j per thread
            }
            // wave argmin (tie -> lower index)
            #pragma unroll
            for (int off = 32; off > 0; off >>= 1) {
                double ov = __shfl_down(bv, off, 64);
                int    oj = __shfl_down(bj, off, 64);
                if (ov < bv || (ov == bv && oj < bj)) { bv = ov; bj = oj; }
            }
            if ((tid & 63) == 0) { redV[tid >> 6] = bv; redJ[tid >> 6] = bj; }
            __syncthreads();   // B2: redV/redJ, usedList, s_cnt, used[j0] visible

            double delta = redV[0]; int j1 = redJ[0];
            #pragma unroll
            for (int w = 1; w < NWAVES; ++w) {
                double ov = redV[w]; int oj = redJ[w];
                if (ov < delta || (ov == delta && oj < j1)) { delta = ov; j1 = oj; }
            }
            const int cnt = s_cnt;

            // dual updates: u[p[used]] += delta, v[used] -= delta (rows distinct)
            for (int k = tid; k < cnt; k += SOLVER_THREADS) {
                int ju = usedList[k];
                u[p[ju]] += delta;
                v[ju]    -= delta;
            }
            // minv[free] -= delta
            for (int j = tid + 1; j <= QQ; j += SOLVER_THREADS) {
                if (!(j == j0 || used[j])) minv[j] -= delta;
            }
            __syncthreads();   // B3: updates visible

            j0 = j1;
            if (p[j0] == 0) break;   // uniform across threads
        }

        // augment (serial, short path)
        if (tid == 0) {
            int jj = j0;
            while (jj) { int jn = way[jj]; p[jj] = p[jn]; jj = jn; }
        }
        __syncthreads();
    }

    // row2col: p[j] > 0 -> target p[j]-1 assigned query j-1
    for (int j = tid + 1; j <= QQ; j += SOLVER_THREADS) {
        int pi = p[j];
        if (pi > 0) outq[(size_t)b * TT + (pi - 1)] = (float)(j - 1);
    }
    for (int t = tid; t < TT; t += SOLVER_THREADS)
        outt[(size_t)b * TT + t] = (float)t;
}

// ---------------------------------------------------------------------------
extern "C" void kernel_launch(void* const* d_in, const int* in_sizes, int n_in,
                              void* d_out, int out_size, void* d_ws, size_t ws_size,
                              hipStream_t stream)
{
    const float* logits  = (const float*)d_in[0];
    const float* pboxes  = (const float*)d_in[1];
    const float* pcut    = (const float*)d_in[2];
    const int*   tlabels = (const int*)d_in[3];
    const float* tboxes  = (const float*)d_in[4];
    const float* tcut    = (const float*)d_in[5];

    float* out  = (float*)d_out;
    float* Cmat = out;                                   // B*Q*T
    float* outq = out + (size_t)BB * QQ * TT;            // B*T
    float* outt = outq + (size_t)BB * TT;                // B*T

    const size_t statsBytes = (size_t)BB * QQ * sizeof(float2);   // 230,400
    const size_t ctBytes    = (size_t)BB * TT * QQ * sizeof(float); // 34.56 MB
    float2* stats = (float2*)d_ws;
    bool haveCT = (ws_size >= statsBytes + ctBytes);
    float* CT = haveCT ? (float*)((char*)d_ws + statsBytes) : nullptr;

    softmax_stats_kernel<<<BB * QQ, 256, 0, stream>>>(logits, stats);

    dim3 grid((QQ + 31) / 32, (TT + 31) / 32, BB);
    cost_kernel<<<grid, 256, 0, stream>>>(logits, pboxes, pcut, tlabels, tboxes,
                                          tcut, stats, Cmat, CT);

    if (haveCT) {
        // CT[b][t][q]: contiguous rows of length QQ
        lsa_kernel<<<BB, SOLVER_THREADS, 0, stream>>>(
            CT, (long long)TT * QQ, (long long)QQ, 1LL, outq, outt);
    } else {
        // read strided directly from Cmat[b][q][t]: row stride 1, col stride TT
        lsa_kernel<<<BB, SOLVER_THREADS, 0, stream>>>(
            Cmat, (long long)QQ * TT, 1LL, (long long)TT, outq, outt);
    }
}

// Round 2
// 1021.558 us; speedup vs baseline: 1.1099x; 1.1099x over previous
//
#include <hip/hip_runtime.h>
#include <float.h>

#define BB 32
#define QQ 900
#define TT 300
#define CC 256

// ---------------------------------------------------------------------------
// Kernel A: per-(b,q) softmax stats: rowmax and sum(exp(l - max))
// ---------------------------------------------------------------------------
__global__ __launch_bounds__(256)
void softmax_stats_kernel(const float* __restrict__ logits, float2* __restrict__ stats)
{
    const int row = blockIdx.x;                 // b*QQ + q
    const float* L = logits + (size_t)row * CC;
    const int tid = threadIdx.x;
    float x = L[tid];

    __shared__ float sredm[4];
    __shared__ float sreds[4];

    float m = x;
    #pragma unroll
    for (int off = 32; off > 0; off >>= 1)
        m = fmaxf(m, __shfl_down(m, off, 64));
    if ((tid & 63) == 0) sredm[tid >> 6] = m;
    __syncthreads();
    m = fmaxf(fmaxf(sredm[0], sredm[1]), fmaxf(sredm[2], sredm[3]));

    float s = expf(x - m);
    #pragma unroll
    for (int off = 32; off > 0; off >>= 1)
        s += __shfl_down(s, off, 64);
    if ((tid & 63) == 0) sreds[tid >> 6] = s;
    __syncthreads();
    if (tid == 0)
        stats[row] = make_float2(m, sreds[0] + sreds[1] + sreds[2] + sreds[3]);
}

// ---------------------------------------------------------------------------
// Kernel B: cost matrix, 32q x 32t tiles. Writes Cmat [b][q][t] coalesced and
// (via LDS transpose) CT [b][t][q] coalesced.
// ---------------------------------------------------------------------------
__global__ __launch_bounds__(256)
void cost_kernel(const float* __restrict__ logits,
                 const float* __restrict__ pboxes,
                 const float* __restrict__ pcut,
                 const int*   __restrict__ tlabels,
                 const float* __restrict__ tboxes,
                 const float* __restrict__ tcut,
                 const float2* __restrict__ stats,
                 float* __restrict__ Cmat,
                 float* __restrict__ CT)
{
    const int b  = blockIdx.z;
    const int q0 = blockIdx.x * 32;
    const int t0 = blockIdx.y * 32;
    const int tid = threadIdx.x;

    __shared__ float s_pb[32][4], s_tb[32][4];
    __shared__ float s_pc[32], s_tc[32], s_pm[32], s_ps[32], s_pa[32], s_ta[32];
    __shared__ int   s_tl[32];
    __shared__ float s_tile[32][33];

    if (tid < 32) {
        int q = q0 + tid;
        if (q < QQ) {
            const float* pb = pboxes + ((size_t)b * QQ + q) * 4;
            float x1 = pb[0], y1 = pb[1], x2 = pb[2], y2 = pb[3];
            s_pb[tid][0] = x1; s_pb[tid][1] = y1; s_pb[tid][2] = x2; s_pb[tid][3] = y2;
            s_pa[tid] = (x2 - x1) * (y2 - y1);
            s_pc[tid] = pcut[(size_t)b * QQ + q];
            float2 st = stats[(size_t)b * QQ + q];
            s_pm[tid] = st.x; s_ps[tid] = st.y;
        }
    } else if (tid < 64) {
        int tl = tid - 32;
        int t = t0 + tl;
        if (t < TT) {
            const float* tb = tboxes + ((size_t)b * TT + t) * 4;
            float x1 = tb[0], y1 = tb[1], x2 = tb[2], y2 = tb[3];
            s_tb[tl][0] = x1; s_tb[tl][1] = y1; s_tb[tl][2] = x2; s_tb[tl][3] = y2;
            s_ta[tl] = (x2 - x1) * (y2 - y1);
            s_tc[tl] = tcut[(size_t)b * TT + t];
            s_tl[tl] = tlabels[(size_t)b * TT + t];
        }
    }
    __syncthreads();

    const int tl = tid & 31;
    const int t  = t0 + tl;
    #pragma unroll
    for (int k = 0; k < 4; ++k) {
        int ql = (tid >> 5) + 8 * k;
        int q  = q0 + ql;
        if (q < QQ && t < TT) {
            float lg = logits[((size_t)b * QQ + q) * CC + s_tl[tl]];
            float cclass = -(expf(lg - s_pm[ql]) / s_ps[ql]);

            float px1 = s_pb[ql][0], py1 = s_pb[ql][1], px2 = s_pb[ql][2], py2 = s_pb[ql][3];
            float tx1 = s_tb[tl][0], ty1 = s_tb[tl][1], tx2 = s_tb[tl][2], ty2 = s_tb[tl][3];

            float l1 = fabsf(px1 - tx1) + fabsf(py1 - ty1) + fabsf(px2 - tx2) + fabsf(py2 - ty2);

            float iw = fmaxf(fminf(px2, tx2) - fmaxf(px1, tx1), 0.0f);
            float ih = fmaxf(fminf(py2, ty2) - fmaxf(py1, ty1), 0.0f);
            float inter = iw * ih;
            float uni = s_pa[ql] + s_ta[tl] - inter;
            float iou = inter / uni;

            float ew = fmaxf(fmaxf(px2, tx2) - fminf(px1, tx1), 0.0f);
            float eh = fmaxf(fmaxf(py2, ty2) - fminf(py1, ty1), 0.0f);
            float enc = ew * eh;
            float giou = iou - (enc - uni) / enc;

            float cost = 5.0f * l1 + cclass - 2.0f * giou
                       + 2.0f * fabsf(s_pc[ql] - s_tc[tl]);

            Cmat[((size_t)b * QQ + q) * TT + t] = cost;
            s_tile[ql][tl] = cost;
        }
    }
    __syncthreads();

    if (CT != nullptr) {
        #pragma unroll
        for (int k = 0; k < 4; ++k) {
            int tl2 = (tid >> 5) + 8 * k;
            int ql2 = tid & 31;
            int t2 = t0 + tl2, q2 = q0 + ql2;
            if (q2 < QQ && t2 < TT)
                CT[((size_t)b * TT + t2) * QQ + q2] = s_tile[ql2][tl2];
        }
    }
}

// ---------------------------------------------------------------------------
// Kernel C: JV shortest-augmenting-path LSA with deferred dual updates.
// sv[j] = minv[j] + D (D = cumulative delta) is invariant under the per-
// iteration "minv -= delta" sweep, so each Dijkstra iteration is ONE scan +
// ONE barrier. sv and used-flags live in registers (4 strided cols/thread).
// Dual updates applied once per row from (usedList, Dent) records.
// Exact same comparison ordering / tie-breaking as the numpy reference.
// ---------------------------------------------------------------------------
#define STH 256
#define NW (STH / 64)
#define KCOLS 4                 // ceil(QQ / STH)

__global__ __launch_bounds__(STH)
void lsa_kernel(const float* __restrict__ Mbase,
                long long batchStride, long long rowStride, long long colStride,
                float* __restrict__ outq, float* __restrict__ outt)
{
    const int b = blockIdx.x;
    const float* M = Mbase + (size_t)b * batchStride;
    const int tid = threadIdx.x;
    const double INFD = 1e300;

    __shared__ double u0[TT + 1];
    __shared__ double v0[QQ + 1];
    __shared__ int    p[QQ + 1];
    __shared__ int    way[QQ + 1];
    __shared__ int    usedList[TT + 1];
    __shared__ double Dent[TT + 1];
    __shared__ double redV[2][NW];
    __shared__ int    redJ[2][NW];

    for (int j = tid; j <= QQ; j += STH) { v0[j] = 0.0; p[j] = 0; way[j] = 0; }
    for (int i = tid; i <= TT; i += STH) u0[i] = 0.0;
    __syncthreads();

    int par = 0;
    for (int i = 1; i <= TT; ++i) {
        double sv[KCOLS];
        #pragma unroll
        for (int k = 0; k < KCOLS; ++k) sv[k] = INFD;
        unsigned usedMask = 0;
        int cnt = 1;            // slot 0 = virtual column 0 (Dent 0)
        double D = 0.0;
        int i0 = i;
        int j0 = 0;
        int j1free;

        while (true) {
            const float* Mrow = M + (long long)(i0 - 1) * rowStride;
            const double u0i0 = u0[i0];

            // issue row loads early (coalesced when colStride==1)
            float mload[KCOLS];
            #pragma unroll
            for (int k = 0; k < KCOLS; ++k) {
                int c = tid + STH * k;
                mload[k] = (c < QQ) ? Mrow[(long long)c * colStride] : 0.0f;
            }

            double bv = INFD; int bj = QQ + 1;
            #pragma unroll
            for (int k = 0; k < KCOLS; ++k) {
                int c = tid + STH * k;
                if (c < QQ && !((usedMask >> k) & 1u)) {
                    int j = c + 1;
                    double cur = (double)mload[k] - u0i0 - v0[j] + D;
                    if (cur < sv[k]) { sv[k] = cur; way[j] = j0; }
                    if (sv[k] < bv) { bv = sv[k]; bj = j; }   // ascending j order
                }
            }
            // wave argmin (tie -> lower j)
            #pragma unroll
            for (int off = 32; off > 0; off >>= 1) {
                double ov = __shfl_down(bv, off, 64);
                int    oj = __shfl_down(bj, off, 64);
                if (ov < bv || (ov == bv && oj < bj)) { bv = ov; bj = oj; }
            }
            if ((tid & 63) == 0) { redV[par][tid >> 6] = bv; redJ[par][tid >> 6] = bj; }
            __syncthreads();                      // the ONLY per-iteration barrier

            double mv = redV[par][0]; int mj = redJ[par][0];
            #pragma unroll
            for (int w = 1; w < NW; ++w) {
                double ov = redV[par][w]; int oj = redJ[par][w];
                if (ov < mv || (ov == mv && oj < mj)) { mv = ov; mj = oj; }
            }
            par ^= 1;                             // double-buffered reduce slots

            int j1 = mj;
            D = mv;                               // new cumulative delta
            int i1 = p[j1];
            if (i1 == 0) { j1free = j1; break; }

            // mark j1 used in its owner's register mask
            int ck = j1 - 1 - tid;
            if (ck >= 0 && (ck & (STH - 1)) == 0) usedMask |= 1u << (ck >> 8);
            if (tid == 0) { usedList[cnt] = j1; Dent[cnt] = D; }
            cnt++;
            j0 = j1; i0 = i1;
        }

        __syncthreads();   // A: way[]/usedList/Dent writes visible; scans done

        // deferred dual updates (reads PRE-augment p; rows & cols distinct)
        for (int k = tid; k < cnt; k += STH) {
            if (k == 0) {
                u0[i] += D;
            } else {
                int ju = usedList[k];
                double d = D - Dent[k];
                u0[p[ju]] += d;
                v0[ju]    -= d;
            }
        }
        __syncthreads();   // B: dual updates done, p reads done

        if (tid == 0) {
            int jj = j1free;
            while (jj) {
                int jn = way[jj];
                p[jj] = (jn == 0) ? i : p[jn];
                jj = jn;
            }
        }
        __syncthreads();   // C: augmented p visible
    }

    // row2col: p[j] > 0 -> target p[j]-1 assigned query j-1
    for (int j = tid + 1; j <= QQ; j += STH) {
        int pi = p[j];
        if (pi > 0) outq[(size_t)b * TT + (pi - 1)] = (float)(j - 1);
    }
    for (int t = tid; t < TT; t += STH)
        outt[(size_t)b * TT + t] = (float)t;
}

// ---------------------------------------------------------------------------
extern "C" void kernel_launch(void* const* d_in, const int* in_sizes, int n_in,
                              void* d_out, int out_size, void* d_ws, size_t ws_size,
                              hipStream_t stream)
{
    const float* logits  = (const float*)d_in[0];
    const float* pboxes  = (const float*)d_in[1];
    const float* pcut    = (const float*)d_in[2];
    const int*   tlabels = (const int*)d_in[3];
    const float* tboxes  = (const float*)d_in[4];
    const float* tcut    = (const float*)d_in[5];

    float* out  = (float*)d_out;
    float* Cmat = out;                                   // B*Q*T
    float* outq = out + (size_t)BB * QQ * TT;            // B*T
    float* outt = outq + (size_t)BB * TT;                // B*T

    const size_t statsBytes = (size_t)BB * QQ * sizeof(float2);     // 230,400
    const size_t ctBytes    = (size_t)BB * TT * QQ * sizeof(float); // 34.56 MB
    float2* stats = (float2*)d_ws;
    bool haveCT = (ws_size >= statsBytes + ctBytes);
    float* CT = haveCT ? (float*)((char*)d_ws + statsBytes) : nullptr;

    softmax_stats_kernel<<<BB * QQ, 256, 0, stream>>>(logits, stats);

    dim3 grid((QQ + 31) / 32, (TT + 31) / 32, BB);
    cost_kernel<<<grid, 256, 0, stream>>>(logits, pboxes, pcut, tlabels, tboxes,
                                          tcut, stats, Cmat, CT);

    if (haveCT) {
        lsa_kernel<<<BB, STH, 0, stream>>>(
            CT, (long long)TT * QQ, (long long)QQ, 1LL, outq, outt);
    } else {
        lsa_kernel<<<BB, STH, 0, stream>>>(
            Cmat, (long long)QQ * TT, 1LL, (long long)TT, outq, outt);
    }
}

// Round 3
// 652.295 us; speedup vs baseline: 1.7382x; 1.5661x over previous
//
#include <hip/hip_runtime.h>
#include <float.h>

#define BB 32
#define QQ 900
#define TT 300
#define CC 256

// ---------------------------------------------------------------------------
// Kernel A: per-(b,q) softmax stats: rowmax and sum(exp(l - max))
// ---------------------------------------------------------------------------
__global__ __launch_bounds__(256)
void softmax_stats_kernel(const float* __restrict__ logits, float2* __restrict__ stats)
{
    const int row = blockIdx.x;                 // b*QQ + q
    const float* L = logits + (size_t)row * CC;
    const int tid = threadIdx.x;
    float x = L[tid];

    __shared__ float sredm[4];
    __shared__ float sreds[4];

    float m = x;
    #pragma unroll
    for (int off = 32; off > 0; off >>= 1)
        m = fmaxf(m, __shfl_down(m, off, 64));
    if ((tid & 63) == 0) sredm[tid >> 6] = m;
    __syncthreads();
    m = fmaxf(fmaxf(sredm[0], sredm[1]), fmaxf(sredm[2], sredm[3]));

    float s = expf(x - m);
    #pragma unroll
    for (int off = 32; off > 0; off >>= 1)
        s += __shfl_down(s, off, 64);
    if ((tid & 63) == 0) sreds[tid >> 6] = s;
    __syncthreads();
    if (tid == 0)
        stats[row] = make_float2(m, sreds[0] + sreds[1] + sreds[2] + sreds[3]);
}

// ---------------------------------------------------------------------------
// Kernel B: cost matrix, 32q x 32t tiles. Writes Cmat [b][q][t] coalesced and
// (via LDS transpose) CT [b][t][q] coalesced.
// ---------------------------------------------------------------------------
__global__ __launch_bounds__(256)
void cost_kernel(const float* __restrict__ logits,
                 const float* __restrict__ pboxes,
                 const float* __restrict__ pcut,
                 const int*   __restrict__ tlabels,
                 const float* __restrict__ tboxes,
                 const float* __restrict__ tcut,
                 const float2* __restrict__ stats,
                 float* __restrict__ Cmat,
                 float* __restrict__ CT)
{
    const int b  = blockIdx.z;
    const int q0 = blockIdx.x * 32;
    const int t0 = blockIdx.y * 32;
    const int tid = threadIdx.x;

    __shared__ float s_pb[32][4], s_tb[32][4];
    __shared__ float s_pc[32], s_tc[32], s_pm[32], s_ps[32], s_pa[32], s_ta[32];
    __shared__ int   s_tl[32];
    __shared__ float s_tile[32][33];

    if (tid < 32) {
        int q = q0 + tid;
        if (q < QQ) {
            const float* pb = pboxes + ((size_t)b * QQ + q) * 4;
            float x1 = pb[0], y1 = pb[1], x2 = pb[2], y2 = pb[3];
            s_pb[tid][0] = x1; s_pb[tid][1] = y1; s_pb[tid][2] = x2; s_pb[tid][3] = y2;
            s_pa[tid] = (x2 - x1) * (y2 - y1);
            s_pc[tid] = pcut[(size_t)b * QQ + q];
            float2 st = stats[(size_t)b * QQ + q];
            s_pm[tid] = st.x; s_ps[tid] = st.y;
        }
    } else if (tid < 64) {
        int tl = tid - 32;
        int t = t0 + tl;
        if (t < TT) {
            const float* tb = tboxes + ((size_t)b * TT + t) * 4;
            float x1 = tb[0], y1 = tb[1], x2 = tb[2], y2 = tb[3];
            s_tb[tl][0] = x1; s_tb[tl][1] = y1; s_tb[tl][2] = x2; s_tb[tl][3] = y2;
            s_ta[tl] = (x2 - x1) * (y2 - y1);
            s_tc[tl] = tcut[(size_t)b * TT + t];
            s_tl[tl] = tlabels[(size_t)b * TT + t];
        }
    }
    __syncthreads();

    const int tl = tid & 31;
    const int t  = t0 + tl;
    #pragma unroll
    for (int k = 0; k < 4; ++k) {
        int ql = (tid >> 5) + 8 * k;
        int q  = q0 + ql;
        if (q < QQ && t < TT) {
            float lg = logits[((size_t)b * QQ + q) * CC + s_tl[tl]];
            float cclass = -(expf(lg - s_pm[ql]) / s_ps[ql]);

            float px1 = s_pb[ql][0], py1 = s_pb[ql][1], px2 = s_pb[ql][2], py2 = s_pb[ql][3];
            float tx1 = s_tb[tl][0], ty1 = s_tb[tl][1], tx2 = s_tb[tl][2], ty2 = s_tb[tl][3];

            float l1 = fabsf(px1 - tx1) + fabsf(py1 - ty1) + fabsf(px2 - tx2) + fabsf(py2 - ty2);

            float iw = fmaxf(fminf(px2, tx2) - fmaxf(px1, tx1), 0.0f);
            float ih = fmaxf(fminf(py2, ty2) - fmaxf(py1, ty1), 0.0f);
            float inter = iw * ih;
            float uni = s_pa[ql] + s_ta[tl] - inter;
            float iou = inter / uni;

            float ew = fmaxf(fmaxf(px2, tx2) - fminf(px1, tx1), 0.0f);
            float eh = fmaxf(fmaxf(py2, ty2) - fminf(py1, ty1), 0.0f);
            float enc = ew * eh;
            float giou = iou - (enc - uni) / enc;

            float cost = 5.0f * l1 + cclass - 2.0f * giou
                       + 2.0f * fabsf(s_pc[ql] - s_tc[tl]);

            Cmat[((size_t)b * QQ + q) * TT + t] = cost;
            s_tile[ql][tl] = cost;
        }
    }
    __syncthreads();

    if (CT != nullptr) {
        #pragma unroll
        for (int k = 0; k < 4; ++k) {
            int tl2 = (tid >> 5) + 8 * k;
            int ql2 = tid & 31;
            int t2 = t0 + tl2, q2 = q0 + ql2;
            if (q2 < QQ && t2 < TT)
                CT[((size_t)b * TT + t2) * QQ + q2] = s_tile[ql2][tl2];
        }
    }
}

// ---------------------------------------------------------------------------
// Kernel C: JV LSA = row reduction + greedy init + shortest augmenting paths.
// Exactness: after u[i]=rowmin, v=0, reduced costs >=0 and greedy-assigned
// pairs are tight (complementary slackness) -> SAP from these duals yields the
// optimal assignment, which is unique for continuous random costs and thus
// identical to the reference's.
// Per Dijkstra iteration: ONE barrier; argmin via packed u64 keys
//   key = (mono_fp64(cur) & ~2047) | (j<<1) | isMatchingFree(j)
// so the break test needs no LDS read. v0/p frozen during a row's search ->
// cached in registers. Dual updates deferred to once per row.
// ---------------------------------------------------------------------------
#define STH 256
#define NW (STH / 64)
#define KCOLS 4                 // ceil(QQ / STH); usedMask bit = col_chunk index

__global__ __launch_bounds__(STH)
void lsa_kernel(const float* __restrict__ Mbase,
                long long batchStride, long long rowStride, long long colStride,
                const float* __restrict__ CmatAll,   // [b][q][t] for row-min phase
                float* __restrict__ outq, float* __restrict__ outt)
{
    const int b = blockIdx.x;
    const float* M  = Mbase + (size_t)b * batchStride;
    const float* Cm = CmatAll + (size_t)b * QQ * TT;
    const int tid = threadIdx.x;

    __shared__ double u0[TT + 1];
    __shared__ double v0[QQ + 1];
    __shared__ int    p[QQ + 1];
    __shared__ int    way[QQ + 1];
    __shared__ int    rowArg[TT + 1];
    __shared__ int    claim[QQ + 1];
    __shared__ int    freeRows[TT];
    __shared__ int    nFreeS;
    __shared__ int    usedList[TT + 1];
    __shared__ double Dent[TT + 1];
    __shared__ unsigned long long redK[2][NW];

    for (int j = tid; j <= QQ; j += STH) { v0[j] = 0.0; p[j] = 0; way[j] = 0; claim[j] = 0x7FFFFFFF; }
    __syncthreads();

    // ---- Phase 1: row reduction. u0[i] = min_j M[i][j], rowArg = argmin.
    // Read from q-major Cmat so loads coalesce across threads (thread = target).
    {
        int r1 = tid;                        // 0..255  (< TT=300)
        int r2 = tid + STH;                  // valid when < TT (tid < 44)
        float b1 = FLT_MAX, b2 = FLT_MAX; int a1 = 1, a2 = 1;
        bool has2 = (r2 < TT);
        for (int q = 0; q < QQ; ++q) {
            float c1 = Cm[(size_t)q * TT + r1];
            if (c1 < b1) { b1 = c1; a1 = q + 1; }
            if (has2) {
                float c2 = Cm[(size_t)q * TT + r2];
                if (c2 < b2) { b2 = c2; a2 = q + 1; }
            }
        }
        u0[r1 + 1] = (double)b1; rowArg[r1 + 1] = a1;
        if (has2) { u0[r2 + 1] = (double)b2; rowArg[r2 + 1] = a2; }
    }
    __syncthreads();

    // ---- Phase 2: greedy — earliest row claims its argmin column.
    for (int i = tid + 1; i <= TT; i += STH) atomicMin(&claim[rowArg[i]], i);
    __syncthreads();
    if (tid == 0) {
        int nf = 0;
        for (int i = 1; i <= TT; ++i) {
            int j = rowArg[i];
            if (claim[j] == i) p[j] = i;
            else freeRows[nf++] = i;
        }
        nFreeS = nf;
    }
    __syncthreads();
    const int nFree = nFreeS;

    // ---- Phase 3: shortest augmenting path for each unassigned row.
    int par = 0;
    for (int f = 0; f < nFree; ++f) {
        const int i = freeRows[f];

        unsigned long long sv[KCOLS];
        double v0r[KCOLS];
        unsigned long long fb[KCOLS];
        bool valid[KCOLS];
        #pragma unroll
        for (int k = 0; k < KCOLS; ++k) {
            int c = tid + STH * k; int j = c + 1;
            valid[k] = (c < QQ);
            sv[k] = ~0ull;
            v0r[k] = valid[k] ? v0[j] : 0.0;
            fb[k]  = (valid[k] && p[j] == 0) ? 1ull : 0ull;
        }
        unsigned usedMask = 0;
        int cnt = 1; double D = 0.0; int i0 = i; int j0 = 0; int j1free;

        while (true) {
            const float* Mrow = M + (long long)(i0 - 1) * rowStride;
            float mload[KCOLS];
            #pragma unroll
            for (int k = 0; k < KCOLS; ++k) {
                int c = tid + STH * k;
                mload[k] = valid[k] ? Mrow[(long long)c * colStride] : 0.0f;
            }
            const double base = D - u0[i0];

            unsigned long long bk = ~0ull;
            #pragma unroll
            for (int k = 0; k < KCOLS; ++k) {
                if (valid[k] && !((usedMask >> k) & 1u)) {
                    int j = tid + STH * k + 1;
                    double cur = (double)mload[k] + (base - v0r[k]);
                    unsigned long long ub = (unsigned long long)__double_as_longlong(cur);
                    unsigned long long mono = (ub & 0x8000000000000000ull)
                                            ? ~ub : (ub | 0x8000000000000000ull);
                    unsigned long long key = (mono & ~2047ull)
                                           | ((unsigned long long)j << 1) | fb[k];
                    if (key < sv[k]) { sv[k] = key; way[j] = j0; }
                    if (sv[k] < bk) bk = sv[k];
                }
            }
            #pragma unroll
            for (int off = 32; off > 0; off >>= 1) {
                unsigned long long ok = __shfl_down(bk, off, 64);
                if (ok < bk) bk = ok;
            }
            if ((tid & 63) == 0) redK[par][tid >> 6] = bk;
            __syncthreads();                       // the ONLY per-iteration barrier
            unsigned long long kmin = redK[par][0];
            #pragma unroll
            for (int w = 1; w < NW; ++w) {
                unsigned long long o = redK[par][w];
                if (o < kmin) kmin = o;
            }
            par ^= 1;

            // recover cumulative distance D from the truncated mono bits
            unsigned long long monoM = kmin & ~2047ull;
            unsigned long long ubM = (monoM >> 63) ? (monoM & 0x7FFFFFFFFFFFFFFFull)
                                                   : ~monoM;
            D = __longlong_as_double((long long)ubM);
            int j1 = (int)((kmin >> 1) & 1023ull);
            if (kmin & 1ull) { j1free = j1; break; }   // hit matching-free column

            int i1 = p[j1];
            int ck = j1 - 1 - tid;
            if (ck >= 0 && (ck & (STH - 1)) == 0) usedMask |= 1u << (ck >> 8);
            if (tid == 0) { usedList[cnt] = j1; Dent[cnt] = D; }
            cnt++;
            j0 = j1; i0 = i1;
        }

        __syncthreads();   // A: way/usedList/Dent visible, scans done

        // deferred dual updates (reads PRE-augment p; rows & cols distinct)
        for (int k = tid; k < cnt; k += STH) {
            if (k == 0) {
                u0[i] += D;
            } else {
                int ju = usedList[k];
                double d = D - Dent[k];
                u0[p[ju]] += d;
                v0[ju]    -= d;
            }
        }
        __syncthreads();   // B

        if (tid == 0) {
            int jj = j1free;
            while (jj) {
                int jn = way[jj];
                p[jj] = (jn == 0) ? i : p[jn];
                jj = jn;
            }
        }
        __syncthreads();   // C
    }

    // row2col: p[j] > 0 -> target p[j]-1 assigned query j-1
    for (int j = tid + 1; j <= QQ; j += STH) {
        int pi = p[j];
        if (pi > 0) outq[(size_t)b * TT + (pi - 1)] = (float)(j - 1);
    }
    for (int t = tid; t < TT; t += STH)
        outt[(size_t)b * TT + t] = (float)t;
}

// ---------------------------------------------------------------------------
extern "C" void kernel_launch(void* const* d_in, const int* in_sizes, int n_in,
                              void* d_out, int out_size, void* d_ws, size_t ws_size,
                              hipStream_t stream)
{
    const float* logits  = (const float*)d_in[0];
    const float* pboxes  = (const float*)d_in[1];
    const float* pcut    = (const float*)d_in[2];
    const int*   tlabels = (const int*)d_in[3];
    const float* tboxes  = (const float*)d_in[4];
    const float* tcut    = (const float*)d_in[5];

    float* out  = (float*)d_out;
    float* Cmat = out;                                   // B*Q*T
    float* outq = out + (size_t)BB * QQ * TT;            // B*T
    float* outt = outq + (size_t)BB * TT;                // B*T

    const size_t statsBytes = (size_t)BB * QQ * sizeof(float2);     // 230,400
    const size_t ctBytes    = (size_t)BB * TT * QQ * sizeof(float); // 34.56 MB
    float2* stats = (float2*)d_ws;
    bool haveCT = (ws_size >= statsBytes + ctBytes);
    float* CT = haveCT ? (float*)((char*)d_ws + statsBytes) : nullptr;

    softmax_stats_kernel<<<BB * QQ, 256, 0, stream>>>(logits, stats);

    dim3 grid((QQ + 31) / 32, (TT + 31) / 32, BB);
    cost_kernel<<<grid, 256, 0, stream>>>(logits, pboxes, pcut, tlabels, tboxes,
                                          tcut, stats, Cmat, CT);

    if (haveCT) {
        lsa_kernel<<<BB, STH, 0, stream>>>(
            CT, (long long)TT * QQ, (long long)QQ, 1LL, Cmat, outq, outt);
    } else {
        lsa_kernel<<<BB, STH, 0, stream>>>(
            Cmat, (long long)QQ * TT, 1LL, (long long)TT, Cmat, outq, outt);
    }
}